// Round 2
// baseline (151.052 us; speedup 1.0000x reference)
//
#include <hip/hip_runtime.h>
#include <hip/hip_bf16.h>
#include <cstdint>

// Problem constants (from reference): B=2, M=256, D=256, DE=64
#define BB 2
#define MM 256
#define DD 256
#define DE 64
#define K2 (2*MM)      // 512
#define WM_LD (DD+DE)  // 320, Wm row stride
#define WH_LD (2*DD)   // 512, Wh row stride
#define TM 8           // rows per block in k_pre

// Persistent scratch (fully overwritten every call before being read)
__device__ float g_fproj[BB*MM*DD];   // f @ Wm_f.T
__device__ float g_asph [MM*DD];      // asp @ Wh[:,D:].T
__device__ float g_fnf  [BB*MM];      // f . wa_nf
__device__ float g_aspdot[MM];        // asp . wa_asp

// ---------------------------------------------------------------- copy
__global__ __launch_bounds__(256) void k_copy(const float4* __restrict__ src,
                                              float4* __restrict__ dst, int n4) {
  int i = blockIdx.x * 256 + threadIdx.x;
  if (i < n4) dst[i] = src[i];
}

// ---------------------------------------------------------------- pre:
// f = feats[:,1:] @ Wz.T + bz ; fnf ; aspdot ; fproj = f @ Wm_f.T ; asp_h
__global__ __launch_bounds__(256) void k_pre(const float* __restrict__ feats,
                                             const float* __restrict__ Wz,
                                             const float* __restrict__ bz,
                                             const float* __restrict__ Wa,
                                             const float* __restrict__ Wm,
                                             const float* __restrict__ Wh) {
  const int blk = blockIdx.x;              // 0 .. B*M/TM-1 = 63
  const int b   = (blk * TM) / MM;
  const int m0  = (blk * TM) % MM;
  const int d   = threadIdx.x;

  __shared__ float fin[TM][DD];
  __shared__ float fz [TM][DD];

  #pragma unroll
  for (int r = 0; r < TM; ++r)
    fin[r][d] = feats[((size_t)b*(MM+1) + m0 + r + 1)*DD + d];
  __syncthreads();

  // f rows: thread d computes f[., d]
  float acc[TM];
  #pragma unroll
  for (int r = 0; r < TM; ++r) acc[r] = 0.f;
  {
    const float4* wrow = (const float4*)(Wz + (size_t)d * DD);
    for (int e4 = 0; e4 < DD/4; ++e4) {
      float4 w4 = wrow[e4];
      #pragma unroll
      for (int r = 0; r < TM; ++r) {
        const float* fp = &fin[r][e4*4];
        acc[r] += w4.x*fp[0] + w4.y*fp[1] + w4.z*fp[2] + w4.w*fp[3];
      }
    }
  }
  const float bzd = bz[d];
  #pragma unroll
  for (int r = 0; r < TM; ++r) { acc[r] += bzd; fz[r][d] = acc[r]; }
  __syncthreads();

  // fnf / aspdot: one wave per row (lane-strided dot + shuffle reduce)
  const int wv = d >> 6, lane = d & 63;
  for (int r = wv; r < TM; r += 4) {
    float p = 0.f;
    for (int e = lane; e < DD; e += 64) p += fz[r][e] * Wa[DE + e];
    for (int off = 32; off > 0; off >>= 1) p += __shfl_down(p, off, 64);
    if (lane == 0) g_fnf[b*MM + m0 + r] = p;
  }
  if (b == 0) {
    for (int r = wv; r < TM; r += 4) {
      float p = 0.f;
      for (int e = lane; e < DD; e += 64) p += fz[r][e] * Wa[DE + DD + e];
      for (int off = 32; off > 0; off >>= 1) p += __shfl_down(p, off, 64);
      if (lane == 0) g_aspdot[m0 + r] = p;
    }
  }

  // fproj = f @ Wm_f.T   (Wm_f = Wm[:, DE:])
  #pragma unroll
  for (int r = 0; r < TM; ++r) acc[r] = 0.f;
  {
    const float4* wrow = (const float4*)(Wm + (size_t)d * WM_LD + DE);
    for (int e4 = 0; e4 < DD/4; ++e4) {
      float4 w4 = wrow[e4];
      #pragma unroll
      for (int r = 0; r < TM; ++r) {
        const float* fp = &fz[r][e4*4];
        acc[r] += w4.x*fp[0] + w4.y*fp[1] + w4.z*fp[2] + w4.w*fp[3];
      }
    }
  }
  #pragma unroll
  for (int r = 0; r < TM; ++r) g_fproj[((size_t)b*MM + m0 + r)*DD + d] = acc[r];

  // asp_h = asp @ Wh[:, D:].T   (asp = f of batch 0)
  if (b == 0) {
    #pragma unroll
    for (int r = 0; r < TM; ++r) acc[r] = 0.f;
    const float4* wrow = (const float4*)(Wh + (size_t)d * WH_LD + DD);
    for (int e4 = 0; e4 < DD/4; ++e4) {
      float4 w4 = wrow[e4];
      #pragma unroll
      for (int r = 0; r < TM; ++r) {
        const float* fp = &fz[r][e4*4];
        acc[r] += w4.x*fp[0] + w4.y*fp[1] + w4.z*fp[2] + w4.w*fp[3];
      }
    }
    #pragma unroll
    for (int r = 0; r < TM; ++r) g_asph[(size_t)(m0 + r)*DD + d] = acc[r];
  }
}

// ---------------------------------------------------------------- attn:
// one block per updated row i (16 per batch)
__global__ __launch_bounds__(256) void k_attn(const float* __restrict__ dta,
                                              const int*   __restrict__ adj,
                                              const int*   __restrict__ a_start,
                                              const int*   __restrict__ a_end,
                                              const float* __restrict__ Wa,
                                              const float* __restrict__ Wm,
                                              const float* __restrict__ Wh,
                                              float* __restrict__ out) {
  const int b = blockIdx.x >> 4;
  const int r = blockIdx.x & 15;
  const int i = a_start[b] + r;
  if (i >= a_end[b] || i >= MM) return;   // block-uniform
  const int t = threadIdx.x;

  __shared__ int   act[K2];
  __shared__ float sv [K2];
  __shared__ float red[256];
  __shared__ int   wcnt[4];
  __shared__ float wadep[DE];
  __shared__ float depsh[64*DE];          // 16 KB chunk of dep vectors
  __shared__ float fused_sh[DD];

  if (t < DE) wadep[t] = Wa[t];

  // ---- deterministic active-list compaction (ballot prefix)
  const int lane = t & 63, wv = t >> 6;
  int na = 0;
  for (int phase = 0; phase < 2; ++phase) {
    const int k = phase*256 + t;
    const int mval = (k < MM) ? adj[((size_t)b*MM + i)*MM + k]
                              : adj[((size_t)b*MM + (k - MM))*MM + i];
    const bool on = (mval != 0);
    const unsigned long long bal = __ballot(on);
    if (lane == 0) wcnt[wv] = __popcll(bal);
    __syncthreads();
    int off = na;
    for (int w2 = 0; w2 < wv; ++w2) off += wcnt[w2];
    off += __popcll(bal & ((1ull << lane) - 1ull));
    if (on) act[off] = k;
    na += wcnt[0] + wcnt[1] + wcnt[2] + wcnt[3];
    __syncthreads();
  }

  // ---- s for active k (leaky relu)
  const float aspdot_i = g_aspdot[i];
  for (int j = t; j < na; j += 256) {
    const int k = act[j];
    const float* dv = (k < MM) ? dta + (((size_t)b*MM + i)*MM + k)*DE
                               : dta + (((size_t)b*MM + (k - MM))*MM + i)*DE;
    float s = 0.f;
    const float4* dv4 = (const float4*)dv;
    #pragma unroll
    for (int e4 = 0; e4 < DE/4; ++e4) {
      const float4 v = dv4[e4];
      s += v.x*wadep[4*e4] + v.y*wadep[4*e4+1] + v.z*wadep[4*e4+2] + v.w*wadep[4*e4+3];
    }
    s += g_fnf[b*MM + (k & (MM-1))] + aspdot_i;
    sv[j] = (s > 0.f) ? s : 0.01f * s;
  }
  __syncthreads();

  // ---- masked softmax over active
  float part = -3.4e38f;
  for (int j = t; j < na; j += 256) part = fmaxf(part, sv[j]);
  red[t] = part; __syncthreads();
  for (int s = 128; s > 0; s >>= 1) { if (t < s) red[t] = fmaxf(red[t], red[t+s]); __syncthreads(); }
  const float mx = red[0];
  __syncthreads();
  float psum = 0.f;
  for (int j = t; j < na; j += 256) { float e = expf(sv[j] - mx); sv[j] = e; psum += e; }
  red[t] = psum; __syncthreads();
  for (int s = 128; s > 0; s >>= 1) { if (t < s) red[t] += red[t+s]; __syncthreads(); }
  const float inv = 1.f / red[0];
  __syncthreads();
  for (int j = t; j < na; j += 256) sv[j] *= inv;
  __syncthreads();

  // ---- fused[d] = sum_k w_k * relu(dep_k . Wm_dep[d] + fproj[b, k%M, d])
  const int d = t;
  float wm[DE];
  {
    const float4* wmrow = (const float4*)(Wm + (size_t)d * WM_LD);  // Wm[:, :DE]
    #pragma unroll
    for (int e4 = 0; e4 < DE/4; ++e4) {
      float4 v = wmrow[e4];
      wm[4*e4] = v.x; wm[4*e4+1] = v.y; wm[4*e4+2] = v.z; wm[4*e4+3] = v.w;
    }
  }
  float acc = 0.f;
  for (int base = 0; base < na; base += 64) {
    const int cnt = min(64, na - base);
    const int nf4 = cnt * (DE/4);
    for (int q = t; q < nf4; q += 256) {
      const int jl = q >> 4, e4 = q & 15;
      const int k = act[base + jl];
      const float* dv = (k < MM) ? dta + (((size_t)b*MM + i)*MM + k)*DE
                                 : dta + (((size_t)b*MM + (k - MM))*MM + i)*DE;
      ((float4*)(depsh + jl*DE))[e4] = ((const float4*)dv)[e4];
    }
    __syncthreads();
    for (int jl = 0; jl < cnt; ++jl) {
      const int k = act[base + jl];
      const float* dp = depsh + jl*DE;
      float dot = 0.f;
      #pragma unroll
      for (int e4 = 0; e4 < DE/4; ++e4) {
        const float4 v = *(const float4*)(dp + 4*e4);
        dot += v.x*wm[4*e4] + v.y*wm[4*e4+1] + v.z*wm[4*e4+2] + v.w*wm[4*e4+3];
      }
      float msg = dot + g_fproj[((size_t)b*MM + (k & (MM-1)))*DD + d];
      msg = (msg > 0.f) ? msg : 0.f;
      acc += sv[base + jl] * msg;
    }
    __syncthreads();
  }
  fused_sh[d] = acc;
  __syncthreads();

  // ---- out = relu(fused @ Wh[:, :D].T + asp_h[i])
  const float4* whrow = (const float4*)(Wh + (size_t)d * WH_LD);
  float o = 0.f;
  for (int e4 = 0; e4 < DD/4; ++e4) {
    float4 v = whrow[e4];
    const float* fp = &fused_sh[e4*4];
    o += v.x*fp[0] + v.y*fp[1] + v.z*fp[2] + v.w*fp[3];
  }
  o += g_asph[(size_t)i*DD + d];
  out[((size_t)b*(MM+1) + i + 1)*DD + d] = (o > 0.f) ? o : 0.f;
}

extern "C" void kernel_launch(void* const* d_in, const int* in_sizes, int n_in,
                              void* d_out, int out_size, void* d_ws, size_t ws_size,
                              hipStream_t stream) {
  const float* feats   = (const float*)d_in[0];
  const float* dta     = (const float*)d_in[1];
  const int*   adj     = (const int*)  d_in[2];
  const int*   a_start = (const int*)  d_in[3];
  const int*   a_end   = (const int*)  d_in[4];
  const float* Wz      = (const float*)d_in[5];
  const float* bz      = (const float*)d_in[6];
  const float* Wa      = (const float*)d_in[7];
  const float* Wm      = (const float*)d_in[8];
  const float* Wh      = (const float*)d_in[9];
  float* out = (float*)d_out;

  const int n4 = BB*(MM+1)*DD/4;  // 32896 float4
  k_copy<<<(n4 + 255)/256, 256, 0, stream>>>((const float4*)feats, (float4*)out, n4);
  k_pre <<<BB*MM/TM, 256, 0, stream>>>(feats, Wz, bz, Wa, Wm, Wh);
  k_attn<<<BB*16, 256, 0, stream>>>(dta, adj, a_start, a_end, Wa, Wm, Wh, out);
}

// Round 4
// 148.341 us; speedup vs baseline: 1.0183x; 1.0183x over previous
//
#include <hip/hip_runtime.h>
#include <hip/hip_bf16.h>
#include <cstdint>

// Problem constants (from reference): B=2, M=256, D=256, DE=64
#define BB 2
#define MM 256
#define DD 256
#define DE 64
#define K2 (2*MM)      // 512
#define WM_LD (DD+DE)  // 320, Wm row stride
#define WH_LD (2*DD)   // 512, Wh row stride

// Persistent scratch (fully overwritten every call before being read)
__device__ float g_fz   [MM*DD];      // batch-0 f rows (for asp use in k_attn)
__device__ float g_fproj[BB*MM*DD];   // f @ Wm_f.T
__device__ float g_fnf  [BB*MM];      // f . wa_nf
__device__ float g_WzT  [DD*DD];      // WzT[e][d] = Wz[d][e]
__device__ float g_WmT  [DD*DD];      // WmT[e][d] = Wm[d][DE+e]

// ------------------------------------------------ transpose weights + copy out
// 512 blocks: blk<256 -> Wz row d, blk>=256 -> Wm_f row d. Also grid-strided
// float4 copy of features -> out (k_attn later overwrites the 32 updated rows).
__global__ __launch_bounds__(256) void k_tr(const float* __restrict__ Wz,
                                            const float* __restrict__ Wm,
                                            const float4* __restrict__ src,
                                            float4* __restrict__ dst, int n4) {
  const int t = threadIdx.x;
  const int blk = blockIdx.x;
  const int d = blk & 255;
  if (blk < 256) g_WzT[t*DD + d] = Wz[(size_t)d*DD + t];
  else           g_WmT[t*DD + d] = Wm[(size_t)d*WM_LD + DE + t];
  const int idx = blk*256 + t;
  if (idx < n4) dst[idx] = src[idx];
}

// ------------------------------------------------ pre (per 2 rows, all 256 d):
// fz = feats[:,1:] @ Wz.T + bz ; fnf = fz . wa_nf ; fproj = fz @ Wm_f.T
__global__ __launch_bounds__(256) void k_pre(const float* __restrict__ feats,
                                             const float* __restrict__ bz,
                                             const float* __restrict__ Wa) {
  const int blk = blockIdx.x;          // 0..255
  const int b   = blk >> 7;
  const int m0  = (blk & 127) * 2;
  const int t   = threadIdx.x;         // = output dim d

  __shared__ float fin[2][DD];
  __shared__ float fzsh[2][DD];

  fin[0][t] = feats[((size_t)b*(MM+1) + m0 + 1)*DD + t];
  fin[1][t] = feats[((size_t)b*(MM+1) + m0 + 2)*DD + t];
  __syncthreads();

  // fz: coalesced WzT streams (lane == d)
  float a0 = 0.f, a1 = 0.f;
  #pragma unroll 8
  for (int e4 = 0; e4 < DD/4; ++e4) {
    const float4 f0 = *(const float4*)&fin[0][e4*4];
    const float4 f1 = *(const float4*)&fin[1][e4*4];
    const float w0 = g_WzT[(e4*4+0)*DD + t];
    const float w1 = g_WzT[(e4*4+1)*DD + t];
    const float w2 = g_WzT[(e4*4+2)*DD + t];
    const float w3 = g_WzT[(e4*4+3)*DD + t];
    a0 += f0.x*w0 + f0.y*w1 + f0.z*w2 + f0.w*w3;
    a1 += f1.x*w0 + f1.y*w1 + f1.z*w2 + f1.w*w3;
  }
  const float bzt = bz[t];
  a0 += bzt; a1 += bzt;
  fzsh[0][t] = a0; fzsh[1][t] = a1;
  if (b == 0) {                         // only batch-0 fz needed later (asp)
    g_fz[(size_t)(m0    )*DD + t] = a0;
    g_fz[(size_t)(m0 + 1)*DD + t] = a1;
  }
  __syncthreads();

  // fnf: waves 0,1 -> rows 0,1
  const int wv = t >> 6, lane = t & 63;
  if (wv < 2) {
    float p = 0.f;
    for (int e = lane; e < DD; e += 64) p += fzsh[wv][e] * Wa[DE + e];
    for (int off = 32; off > 0; off >>= 1) p += __shfl_down(p, off, 64);
    if (lane == 0) g_fnf[b*MM + m0 + wv] = p;
  }

  // fproj = fz @ Wm_f.T : coalesced WmT streams
  float p0 = 0.f, p1 = 0.f;
  #pragma unroll 8
  for (int e4 = 0; e4 < DD/4; ++e4) {
    const float4 f0 = *(const float4*)&fzsh[0][e4*4];
    const float4 f1 = *(const float4*)&fzsh[1][e4*4];
    const float w0 = g_WmT[(e4*4+0)*DD + t];
    const float w1 = g_WmT[(e4*4+1)*DD + t];
    const float w2 = g_WmT[(e4*4+2)*DD + t];
    const float w3 = g_WmT[(e4*4+3)*DD + t];
    p0 += f0.x*w0 + f0.y*w1 + f0.z*w2 + f0.w*w3;
    p1 += f1.x*w0 + f1.y*w1 + f1.z*w2 + f1.w*w3;
  }
  g_fproj[((size_t)b*MM + m0    )*DD + t] = p0;
  g_fproj[((size_t)b*MM + m0 + 1)*DD + t] = p1;
}

// ------------------------------------------------ attn: one block per updated row
__global__ __launch_bounds__(256) void k_attn(const float* __restrict__ dta,
                                              const int*   __restrict__ adj,
                                              const int*   __restrict__ a_start,
                                              const int*   __restrict__ a_end,
                                              const float* __restrict__ Wa,
                                              const float* __restrict__ Wm,
                                              const float* __restrict__ Wh,
                                              float* __restrict__ out) {
  const int b = blockIdx.x >> 4;
  const int r = blockIdx.x & 15;
  const int i = a_start[b] + r;
  if (i >= a_end[b] || i >= MM) return;   // block-uniform
  const int t = threadIdx.x;

  __shared__ int   act[K2];
  __shared__ float sv [K2];
  __shared__ float red[256];
  __shared__ int   wcnt[4];
  __shared__ float wadep[DE];
  __shared__ float fz0[DD];               // asp row i (batch-0 f)
  __shared__ float depsh[64*DE];          // 16 KB chunk of dep vectors
  __shared__ float fused_sh[DD];
  __shared__ float aspd_sh;

  if (t < DE) wadep[t] = Wa[t];
  fz0[t] = g_fz[(size_t)i*DD + t];
  __syncthreads();

  // aspdot_i = asp . wa_asp (deterministic tree)
  red[t] = fz0[t] * Wa[DE + DD + t];
  __syncthreads();
  for (int s = 128; s > 0; s >>= 1) { if (t < s) red[t] += red[t+s]; __syncthreads(); }
  if (t == 0) aspd_sh = red[0];
  __syncthreads();
  const float aspdot_i = aspd_sh;

  // ---- deterministic active-list compaction (ballot prefix)
  const int lane = t & 63, wv = t >> 6;
  int na = 0;
  for (int phase = 0; phase < 2; ++phase) {
    const int k = phase*256 + t;
    const int mval = (k < MM) ? adj[((size_t)b*MM + i)*MM + k]
                              : adj[((size_t)b*MM + (k - MM))*MM + i];
    const bool on = (mval != 0);
    const unsigned long long bal = __ballot(on);
    if (lane == 0) wcnt[wv] = __popcll(bal);
    __syncthreads();
    int off = na;
    for (int w2 = 0; w2 < wv; ++w2) off += wcnt[w2];
    off += __popcll(bal & ((1ull << lane) - 1ull));
    if (on) act[off] = k;
    na += wcnt[0] + wcnt[1] + wcnt[2] + wcnt[3];
    __syncthreads();
  }

  // ---- s for active k (leaky relu)
  for (int j = t; j < na; j += 256) {
    const int k = act[j];
    const float* dv = (k < MM) ? dta + (((size_t)b*MM + i)*MM + k)*DE
                               : dta + (((size_t)b*MM + (k - MM))*MM + i)*DE;
    float s = 0.f;
    const float4* dv4 = (const float4*)dv;
    #pragma unroll
    for (int e4 = 0; e4 < DE/4; ++e4) {
      const float4 v = dv4[e4];
      s += v.x*wadep[4*e4] + v.y*wadep[4*e4+1] + v.z*wadep[4*e4+2] + v.w*wadep[4*e4+3];
    }
    s += g_fnf[b*MM + (k & (MM-1))] + aspdot_i;
    sv[j] = (s > 0.f) ? s : 0.01f * s;
  }
  __syncthreads();

  // ---- masked softmax over active
  float part = -3.4e38f;
  for (int j = t; j < na; j += 256) part = fmaxf(part, sv[j]);
  red[t] = part; __syncthreads();
  for (int s = 128; s > 0; s >>= 1) { if (t < s) red[t] = fmaxf(red[t], red[t+s]); __syncthreads(); }
  const float mx = red[0];
  __syncthreads();
  float psum = 0.f;
  for (int j = t; j < na; j += 256) { float e = expf(sv[j] - mx); sv[j] = e; psum += e; }
  red[t] = psum; __syncthreads();
  for (int s = 128; s > 0; s >>= 1) { if (t < s) red[t] += red[t+s]; __syncthreads(); }
  const float inv = 1.f / red[0];
  __syncthreads();
  for (int j = t; j < na; j += 256) sv[j] *= inv;
  __syncthreads();

  // ---- fused[d] = sum_k w_k * relu(dep_k . Wm_dep[d] + fproj[b, k%M, d])
  const int d = t;
  float wm[DE];
  {
    const float4* wmrow = (const float4*)(Wm + (size_t)d * WM_LD);  // Wm[:, :DE]
    #pragma unroll
    for (int e4 = 0; e4 < DE/4; ++e4) {
      float4 v = wmrow[e4];
      wm[4*e4] = v.x; wm[4*e4+1] = v.y; wm[4*e4+2] = v.z; wm[4*e4+3] = v.w;
    }
  }
  float acc = 0.f;
  for (int base = 0; base < na; base += 64) {
    const int cnt = min(64, na - base);
    const int nf4 = cnt * (DE/4);
    for (int q = t; q < nf4; q += 256) {
      const int jl = q >> 4, e4 = q & 15;
      const int k = act[base + jl];
      const float* dv = (k < MM) ? dta + (((size_t)b*MM + i)*MM + k)*DE
                                 : dta + (((size_t)b*MM + (k - MM))*MM + i)*DE;
      ((float4*)(depsh + jl*DE))[e4] = ((const float4*)dv)[e4];
    }
    __syncthreads();
    for (int jl = 0; jl < cnt; ++jl) {
      const float* dp = depsh + jl*DE;
      float dot = 0.f;
      #pragma unroll
      for (int e4 = 0; e4 < DE/4; ++e4) {
        const float4 v = *(const float4*)(dp + 4*e4);
        dot += v.x*wm[4*e4] + v.y*wm[4*e4+1] + v.z*wm[4*e4+2] + v.w*wm[4*e4+3];
      }
      const int k = act[base + jl];
      float msg = dot + g_fproj[((size_t)b*MM + (k & (MM-1)))*DD + d];
      msg = (msg > 0.f) ? msg : 0.f;
      acc += sv[base + jl] * msg;
    }
    __syncthreads();
  }
  fused_sh[d] = acc;
  __syncthreads();

  // ---- out = relu(fused @ Wh[:, :D].T + asp @ Wh[:, D:].T)
  const float4* whrow = (const float4*)(Wh + (size_t)d * WH_LD);
  float o = 0.f;
  #pragma unroll 4
  for (int e4 = 0; e4 < DD/4; ++e4) {
    const float4 v = whrow[e4];
    const float* fp = &fused_sh[e4*4];
    o += v.x*fp[0] + v.y*fp[1] + v.z*fp[2] + v.w*fp[3];
  }
  #pragma unroll 4
  for (int e4 = 0; e4 < DD/4; ++e4) {
    const float4 v = whrow[DD/4 + e4];
    const float* fp = &fz0[e4*4];
    o += v.x*fp[0] + v.y*fp[1] + v.z*fp[2] + v.w*fp[3];
  }
  out[((size_t)b*(MM+1) + i + 1)*DD + d] = (o > 0.f) ? o : 0.f;
}

extern "C" void kernel_launch(void* const* d_in, const int* in_sizes, int n_in,
                              void* d_out, int out_size, void* d_ws, size_t ws_size,
                              hipStream_t stream) {
  const float* feats   = (const float*)d_in[0];
  const float* dta     = (const float*)d_in[1];
  const int*   adj     = (const int*)  d_in[2];
  const int*   a_start = (const int*)  d_in[3];
  const int*   a_end   = (const int*)  d_in[4];
  const float* Wz      = (const float*)d_in[5];
  const float* bz      = (const float*)d_in[6];
  const float* Wa      = (const float*)d_in[7];
  const float* Wm      = (const float*)d_in[8];
  const float* Wh      = (const float*)d_in[9];
  float* out = (float*)d_out;

  const int n4 = BB*(MM+1)*DD/4;  // 32896 float4
  k_tr  <<<2*DD, 256, 0, stream>>>(Wz, Wm, (const float4*)feats, (float4*)out, n4);
  k_pre <<<BB*MM/2, 256, 0, stream>>>(feats, bz, Wa);
  k_attn<<<BB*16, 256, 0, stream>>>(dta, adj, a_start, a_end, Wa, Wm, Wh, out);
}